// Round 2
// baseline (514.257 us; speedup 1.0000x reference)
//
#include <hip/hip_runtime.h>

#define N_OPS 32
#define D 128
#define EPS 1e-5f
#define LEAK 1e-5f
#define NTOK (8 * 2048)
#define NASSIGN (NTOK * 2)
#define MAT (D * D)            // 16384 floats per matrix
#define LIST_CAP 51200         // 32768 + 32*63 pad + 16384 leak, rounded to 256
#define GRPS (LIST_CAP / 256)  // 200 slot-groups of 256
#define LEAK_FLAG 0x10000

// ---------------------------------------------------------------------------
// ws layout:
//   float w_eff[33][16384]   (expert 32 = leak matrix, pre-scaled by LEAK/32)
//   int   cnt[32]; int cur[32];   <- zeroed by hipMemsetAsync
//   int   off[64];                <- written by scan
//   int   list[LIST_CAP];         <- memset to 0xFF (-1) then scattered into
// ---------------------------------------------------------------------------

// Kernel 1: blocks 0..31 quantize one op each; blocks 32..95 histogram indices.
__global__ __launch_bounds__(256) void k_quant_hist(const float* __restrict__ ops,
                                                    const int* __restrict__ idx,
                                                    float* __restrict__ w_eff,
                                                    int* __restrict__ cnt) {
    if (blockIdx.x < N_OPS) {
        const int n = blockIdx.x;
        const float* W = ops + n * MAT;
        float s = 0.f;
        for (int i = threadIdx.x; i < MAT; i += 256) s += fabsf(W[i]);
        for (int off = 32; off; off >>= 1) s += __shfl_xor(s, off);
        __shared__ float red[4];
        __shared__ float s_scale;
        const int lane = threadIdx.x & 63, wid = threadIdx.x >> 6;
        if (lane == 0) red[wid] = s;
        __syncthreads();
        if (threadIdx.x == 0)
            s_scale = fmaxf((red[0] + red[1] + red[2] + red[3]) / (float)MAT, EPS);
        __syncthreads();
        const float scale = s_scale;
        float* out = w_eff + n * MAT;
        for (int i = threadIdx.x; i < MAT; i += 256) {
            float q = rintf(W[i] / scale);
            q = fminf(1.f, fmaxf(-1.f, q));
            out[i] = q * scale;
        }
    } else {
        // histogram over 32768 assignments
        for (int i = (blockIdx.x - N_OPS) * 256 + threadIdx.x; i < NASSIGN; i += 64 * 256)
            atomicAdd(&cnt[idx[i]], 1);
    }
}

// Kernel 2: serial scan -> 64-aligned segment offsets; off[32] = leak start.
__global__ void k_scan(const int* __restrict__ cnt, int* __restrict__ off) {
    if (threadIdx.x == 0) {
        int run = 0;
        for (int e = 0; e < N_OPS; ++e) {
            off[e] = run;
            run += (cnt[e] + 63) & ~63;
        }
        off[N_OPS] = run;  // leak segment start (64-aligned, length 16384)
    }
}

// Kernel 3: blocks 0..63 scatter assignments + fill leak segment;
//           blocks 64..127 build leak matrix into w_eff[32].
__global__ __launch_bounds__(256) void k_scatter_leak(const int* __restrict__ idx,
                                                      const int* __restrict__ off,
                                                      int* __restrict__ cur,
                                                      int* __restrict__ list,
                                                      float* __restrict__ w_eff) {
    if (blockIdx.x < 64) {
        const int stride = 64 * 256;
        for (int a = blockIdx.x * 256 + threadIdx.x; a < NASSIGN; a += stride) {
            int e = idx[a];
            int p = off[e] + atomicAdd(&cur[e], 1);
            list[p] = (e << 20) | a;
        }
        const int l0 = off[N_OPS];
        for (int t = blockIdx.x * 256 + threadIdx.x; t < NTOK; t += stride)
            list[l0 + t] = (N_OPS << 20) | LEAK_FLAG | t;
    } else {
        const int i = (blockIdx.x - 64) * 256 + threadIdx.x;  // 0..16383
        float s = 0.f;
        for (int n = 0; n < N_OPS; ++n) s += w_eff[n * MAT + i];
        w_eff[N_OPS * MAT + i] = s * (LEAK / (float)N_OPS);
    }
}

// ---------------------------------------------------------------------------
// Main: grid = 4 o-quarters x 200 groups. Wave = 64 slots of ONE expert
// (segments are 64-aligned). Lane owns a token: x in 128 VGPRs, W row
// addresses wave-uniform (scalar path), 32 output rows per wave.
// Epilogue transposes through LDS so atomics go out coalesced.
// ---------------------------------------------------------------------------
__global__ __launch_bounds__(256, 2) void k_main(const float* __restrict__ x,
                                                 const float* __restrict__ wts,
                                                 const int* __restrict__ list,
                                                 const float* __restrict__ w_eff,
                                                 float* __restrict__ out) {
    const int lane = threadIdx.x & 63;
    const int wv   = threadIdx.x >> 6;
    const int oq   = blockIdx.x & 3;   // which 32-row quarter
    const int grp  = blockIdx.x >> 2;  // slot group 0..199

    const int p = grp * 256 + wv * 64 + lane;
    const int v = list[p];
    const int v0 = __builtin_amdgcn_readfirstlane(v);
    if (v0 < 0) return;                     // whole wave is padding
    const int e = (v0 >> 20) & 63;          // wave-uniform expert

    int tok;  float w;
    if (v < 0) { tok = -1; w = 0.f; }
    else {
        int low = v & 0xFFFFF;
        if (low & LEAK_FLAG) { tok = low & 0xFFFF; w = 1.f; }
        else                 { tok = low >> 1;     w = wts[low]; }
    }
    const int tl = tok < 0 ? 0 : tok;

    // x into registers (32 float4 = 128 VGPRs)
    const float4* xp = (const float4*)(x + (size_t)tl * D);
    float4 xv[32];
#pragma unroll
    for (int i = 0; i < 32; ++i) xv[i] = xp[i];

    const float* Wp = w_eff + e * MAT + oq * 32 * D;

    float acc[32];
#pragma unroll 2
    for (int o = 0; o < 32; ++o) {
        const float4* Wr = (const float4*)(Wp + o * D);
        float s0 = 0.f, s1 = 0.f, s2 = 0.f, s3 = 0.f;
#pragma unroll
        for (int i = 0; i < 32; ++i) {
            float4 W4 = Wr[i];
            s0 = fmaf(W4.x, xv[i].x, s0);
            s1 = fmaf(W4.y, xv[i].y, s1);
            s2 = fmaf(W4.z, xv[i].z, s2);
            s3 = fmaf(W4.w, xv[i].w, s3);
        }
        acc[o] = (s0 + s1) + (s2 + s3);
    }

    // Epilogue: transpose 32(o) x 64(token) tile via LDS, coalesced atomics.
    __shared__ float tile[4][16][68];  // [wave][o'][token-lane], pad 68: 2-way free
    const int obase = oq * 32;
#pragma unroll
    for (int r = 0; r < 2; ++r) {
#pragma unroll
        for (int j = 0; j < 16; ++j) tile[wv][j][lane] = acc[r * 16 + j] * w;
        // per-wave LDS ops are in-order; compiler inserts lgkmcnt for the reads
#pragma unroll
        for (int tg = 0; tg < 16; ++tg) {
            int src = tg * 4 + (lane >> 4);          // source token-lane
            int ts  = __shfl(tok, src, 64);          // its token id (-1 = pad)
            float val = tile[wv][lane & 15][src];
            if (ts >= 0)
                atomicAdd(out + (size_t)ts * D + obase + r * 16 + (lane & 15), val);
        }
    }
}

// ---------------------------------------------------------------------------
extern "C" void kernel_launch(void* const* d_in, const int* in_sizes, int n_in,
                              void* d_out, int out_size, void* d_ws, size_t ws_size,
                              hipStream_t stream) {
    const float* x   = (const float*)d_in[0];
    const int*   idx = (const int*)  d_in[1];
    const float* wts = (const float*)d_in[2];
    const float* ops = (const float*)d_in[3];
    float* out = (float*)d_out;

    float* w_eff = (float*)d_ws;                     // 33 * 16384 floats
    int*   cnt   = (int*)(w_eff + 33 * MAT);         // [32]
    int*   cur   = cnt + 32;                         // [32]
    int*   off   = cnt + 64;                         // [64]
    int*   list  = cnt + 128;                        // [LIST_CAP]

    hipMemsetAsync(cnt, 0, 64 * sizeof(int), stream);            // cnt + cur
    hipMemsetAsync(list, 0xFF, LIST_CAP * sizeof(int), stream);  // pads = -1
    hipMemsetAsync(out, 0, (size_t)out_size * sizeof(float), stream);

    k_quant_hist<<<96, 256, 0, stream>>>(ops, idx, w_eff, cnt);
    k_scan<<<1, 64, 0, stream>>>(cnt, off);
    k_scatter_leak<<<128, 256, 0, stream>>>(idx, off, cur, list, w_eff);
    k_main<<<4 * GRPS, 256, 0, stream>>>(x, wts, list, w_eff, out);
}

// Round 3
// 131.232 us; speedup vs baseline: 3.9187x; 3.9187x over previous
//
#include <hip/hip_runtime.h>

#define N_OPS 32
#define D 128
#define MAT (D * D)
#define EPS 1e-5f
#define LEAK 1e-5f
#define NTOK (8 * 2048)
#define NASSIGN (NTOK * 2)
#define CAP 34816                  // 32768 + 32*63 pad, rounded to 256
#define MAIN_BLKS ((CAP / 256) * 4)   // 544
#define LEAK_BLKS ((NTOK / 256) * 4)  // 256

// ---------------------------------------------------------------------------
// A: blocks 0..31 -> scale[n] = max(mean|W_n|, EPS); blocks 32..63 -> per-block
// histogram of 1024 indices each into hist2[block][32] (plain stores).
// ---------------------------------------------------------------------------
__global__ __launch_bounds__(256) void k_scale_hist(const float* __restrict__ ops,
                                                    const int* __restrict__ idx,
                                                    float* __restrict__ scale,
                                                    int* __restrict__ hist2) {
    if (blockIdx.x < N_OPS) {
        const int n = blockIdx.x;
        const float* W = ops + n * MAT;
        float s = 0.f;
        for (int i = threadIdx.x; i < MAT; i += 256) s += fabsf(W[i]);
        for (int off = 32; off; off >>= 1) s += __shfl_xor(s, off);
        __shared__ float red[4];
        const int lane = threadIdx.x & 63, wid = threadIdx.x >> 6;
        if (lane == 0) red[wid] = s;
        __syncthreads();
        if (threadIdx.x == 0)
            scale[n] = fmaxf((red[0] + red[1] + red[2] + red[3]) / (float)MAT, EPS);
    } else {
        const int b = blockIdx.x - N_OPS;
        __shared__ int lh[N_OPS];
        if (threadIdx.x < N_OPS) lh[threadIdx.x] = 0;
        __syncthreads();
#pragma unroll
        for (int j = 0; j < 4; ++j)
            atomicAdd(&lh[idx[b * 1024 + j * 256 + threadIdx.x]], 1);
        __syncthreads();
        if (threadIdx.x < N_OPS) hist2[b * N_OPS + threadIdx.x] = lh[threadIdx.x];
    }
}

// ---------------------------------------------------------------------------
// B: single block. 64-aligned expert segment offsets, per-(block,expert)
// scatter bases, and -1 fill of all pad slots.
// ---------------------------------------------------------------------------
__global__ __launch_bounds__(256) void k_scan(const int* __restrict__ hist2,
                                              int* __restrict__ base2,
                                              int* __restrict__ list) {
    __shared__ int hl[1024];
    __shared__ int totl[N_OPS];
    __shared__ int offl[N_OPS + 1];
    for (int i = threadIdx.x; i < 1024; i += 256) hl[i] = hist2[i];
    __syncthreads();
    if (threadIdx.x < N_OPS) {
        int t = 0;
        for (int b = 0; b < 32; ++b) t += hl[b * N_OPS + threadIdx.x];
        totl[threadIdx.x] = t;
    }
    __syncthreads();
    if (threadIdx.x == 0) {
        int run = 0;
        for (int e = 0; e < N_OPS; ++e) { offl[e] = run; run += (totl[e] + 63) & ~63; }
        offl[N_OPS] = run;
    }
    __syncthreads();
    if (threadIdx.x < N_OPS) {
        const int e = threadIdx.x;
        int running = offl[e];
        for (int b = 0; b < 32; ++b) { base2[b * N_OPS + e] = running; running += hl[b * N_OPS + e]; }
        for (int s = running; s < offl[e + 1]; ++s) list[s] = -1;   // segment tail pads
    }
    for (int s = offl[N_OPS] + (int)threadIdx.x; s < CAP; s += 256) list[s] = -1;
}

// ---------------------------------------------------------------------------
// C: blocks 0..63 quantize+TRANSPOSE one half-matrix each into w_effT
// (LDS 64x129 tile: conflict-free, coalesced in and out). Blocks 64..95
// scatter assignments using only LDS atomics: slot = base2[b][e] + local rank.
// Also writes inverse map slot_of[a].
// ---------------------------------------------------------------------------
__global__ __launch_bounds__(256) void k_apply_scatter(const float* __restrict__ ops,
                                                       const int* __restrict__ idx,
                                                       const float* __restrict__ scale,
                                                       const int* __restrict__ base2,
                                                       float* __restrict__ w_effT,
                                                       int* __restrict__ list,
                                                       int* __restrict__ slot_of) {
    if (blockIdx.x < 64) {
        const int n = blockIdx.x >> 1;
        const int hb = (blockIdx.x & 1) * 64;
        __shared__ float tile[64][129];
        const float sc = scale[n];
        for (int f = threadIdx.x; f < 8192; f += 256) {
            const int ol = f >> 7, d = f & 127;
            const float w = ops[n * MAT + (hb + ol) * D + d];
            const float q = fminf(1.f, fmaxf(-1.f, rintf(w / sc)));  // true divide
            tile[ol][d] = q * sc;
        }
        __syncthreads();
        for (int g = threadIdx.x; g < 8192; g += 256) {
            const int d = g >> 6, ol = g & 63;
            w_effT[n * MAT + d * D + hb + ol] = tile[ol][d];
        }
    } else {
        const int b = blockIdx.x - 64;
        __shared__ int lh[N_OPS];
        if (threadIdx.x < N_OPS) lh[threadIdx.x] = 0;
        __syncthreads();
#pragma unroll
        for (int j = 0; j < 4; ++j) {
            const int a = b * 1024 + j * 256 + threadIdx.x;
            const int e = idx[a];
            const int r = atomicAdd(&lh[e], 1);          // LDS atomic only
            const int slot = base2[b * N_OPS + e] + r;
            list[slot] = (e << 20) | a;
            slot_of[a] = slot;
        }
    }
}

// ---------------------------------------------------------------------------
// D: leak matrix (transposed layout, pre-scaled): LT = (LEAK/32) * sum_n WT_n.
// ---------------------------------------------------------------------------
__global__ __launch_bounds__(256) void k_leakmat(const float* __restrict__ w_effT,
                                                 float* __restrict__ LmatT) {
    const int i = blockIdx.x * 256 + threadIdx.x;
    float s = 0.f;
    for (int n = 0; n < N_OPS; ++n) s += w_effT[n * MAT + i];
    LmatT[i] = s * (LEAK / (float)N_OPS);
}

// ---------------------------------------------------------------------------
// E: main compute. Blocks [0,544): expert slots -> partial[slot][:]; blocks
// [544,800): leak over consecutive tokens -> out[t][:] (direct assign).
// Wave = 64 slots/tokens, lane = one token; d-outer loop, acc[32] for one
// 32-row o-quarter; W rows wave-uniform 128B loads. Epilogue: per-wave LDS
// transpose -> fully coalesced plain stores. No atomics anywhere.
// ---------------------------------------------------------------------------
__global__ __launch_bounds__(256, 3) void k_mainleak(const float* __restrict__ x,
                                                     const int* __restrict__ list,
                                                     const float* __restrict__ w_effT,
                                                     const float* __restrict__ LmatT,
                                                     float* __restrict__ partial,
                                                     float* __restrict__ out) {
    const int lane = threadIdx.x & 63;
    const int wv   = threadIdx.x >> 6;
    int oq, tok;
    const float* Mp;
    float* dstbase;
    if (blockIdx.x < MAIN_BLKS) {
        oq = blockIdx.x & 3;
        const int grp = blockIdx.x >> 2;
        const int p = grp * 256 + wv * 64 + lane;
        const int v = list[p];
        const int v0 = __builtin_amdgcn_readfirstlane(v);
        if (v0 < 0) return;                      // pads are segment tails -> lane0 real unless all pad
        Mp = w_effT + (size_t)(v0 >> 20) * MAT;  // wave-uniform expert
        tok = (v < 0) ? 0 : ((v & 0xFFFFF) >> 1);
        dstbase = partial + (size_t)(grp * 256 + wv * 64) * D;
    } else {
        const int lb = blockIdx.x - MAIN_BLKS;
        oq = lb & 3;
        const int tg = lb >> 2;
        tok = tg * 256 + wv * 64 + lane;
        Mp = LmatT;
        dstbase = out + (size_t)(tg * 256 + wv * 64) * D;
    }
    const int obase = oq * 32;
    const float4* xp4 = (const float4*)(x + (size_t)tok * D);

    float4 acc[8];
#pragma unroll
    for (int j = 0; j < 8; ++j) acc[j] = make_float4(0.f, 0.f, 0.f, 0.f);

#pragma unroll 2
    for (int dd = 0; dd < 32; ++dd) {
        const float4 x4 = xp4[dd];
#pragma unroll
        for (int q = 0; q < 4; ++q) {
            const float xd = (q == 0) ? x4.x : (q == 1) ? x4.y : (q == 2) ? x4.z : x4.w;
            const float4* Wd = (const float4*)(Mp + (dd * 4 + q) * D + obase);
#pragma unroll
            for (int j = 0; j < 8; ++j) {
                const float4 w4 = Wd[j];
                acc[j].x = fmaf(w4.x, xd, acc[j].x);
                acc[j].y = fmaf(w4.y, xd, acc[j].y);
                acc[j].z = fmaf(w4.z, xd, acc[j].z);
                acc[j].w = fmaf(w4.w, xd, acc[j].w);
            }
        }
    }

    // per-wave transpose 32(o) x 64(slot); pad 65 -> <=2-way (free) conflicts
    __shared__ float tile[4][32][65];
#pragma unroll
    for (int j = 0; j < 8; ++j) {
        tile[wv][4 * j + 0][lane] = acc[j].x;
        tile[wv][4 * j + 1][lane] = acc[j].y;
        tile[wv][4 * j + 2][lane] = acc[j].z;
        tile[wv][4 * j + 3][lane] = acc[j].w;
    }
    const int c = lane & 31;
    const int sh = lane >> 5;
#pragma unroll 8
    for (int ss = 0; ss < 32; ++ss) {
        const int s = ss * 2 + sh;
        dstbase[(size_t)s * D + obase + c] = tile[wv][c][s];  // 2x128B segments/instr
    }
}

// ---------------------------------------------------------------------------
// F: finalize. Wave per token: out[t] = leak(out[t]) + w0*partial[s0] + w1*partial[s1].
// ---------------------------------------------------------------------------
__global__ __launch_bounds__(256) void k_final(const float* __restrict__ partial,
                                               const int* __restrict__ slot_of,
                                               const float* __restrict__ wts,
                                               float* __restrict__ out) {
    const int lane = threadIdx.x & 63;
    const int t = blockIdx.x * 4 + (threadIdx.x >> 6);
    const int s0 = slot_of[2 * t], s1 = slot_of[2 * t + 1];
    const float w0 = wts[2 * t], w1 = wts[2 * t + 1];
    const float2 p0 = ((const float2*)(partial + (size_t)s0 * D))[lane];
    const float2 p1 = ((const float2*)(partial + (size_t)s1 * D))[lane];
    float2* op = ((float2*)out) + (size_t)t * 64 + lane;
    float2 o = *op;
    o.x += w0 * p0.x + w1 * p1.x;
    o.y += w0 * p0.y + w1 * p1.y;
    *op = o;
}

// ---------------------------------------------------------------------------
extern "C" void kernel_launch(void* const* d_in, const int* in_sizes, int n_in,
                              void* d_out, int out_size, void* d_ws, size_t ws_size,
                              hipStream_t stream) {
    const float* x   = (const float*)d_in[0];
    const int*   idx = (const int*)  d_in[1];
    const float* wts = (const float*)d_in[2];
    const float* ops = (const float*)d_in[3];
    float* out = (float*)d_out;

    // ws: w_effT 2MB | LmatT 64KB | partial 17.8MB | scale | hist2 | base2 | list | slot_of
    float* w_effT  = (float*)d_ws;
    float* LmatT   = w_effT + N_OPS * MAT;
    float* partial = LmatT + MAT;
    float* scale   = partial + (size_t)CAP * D;
    int*   hist2   = (int*)(scale + 32);
    int*   base2   = hist2 + 1024;
    int*   list    = base2 + 1024;
    int*   slot_of = list + CAP;

    k_scale_hist<<<64, 256, 0, stream>>>(ops, idx, scale, hist2);
    k_scan<<<1, 256, 0, stream>>>(hist2, base2, list);
    k_apply_scatter<<<96, 256, 0, stream>>>(ops, idx, scale, base2, w_effT, list, slot_of);
    k_leakmat<<<64, 256, 0, stream>>>(w_effT, LmatT);
    k_mainleak<<<MAIN_BLKS + LEAK_BLKS, 256, 0, stream>>>(x, list, w_effT, LmatT, partial, out);
    k_final<<<NTOK / 4, 256, 0, stream>>>(partial, slot_of, wts, out);
}

// Round 4
// 112.931 us; speedup vs baseline: 4.5537x; 1.1621x over previous
//
#include <hip/hip_runtime.h>

#define N_OPS 32
#define D 128
#define MAT (D * D)                 // 16384 elements per matrix
#define EPS 1e-5f
#define LEAK 1e-5f
#define NTOK (8 * 2048)
#define NASSIGN (NTOK * 2)
#define CAP 34816                   // 32768 + 32*63 pad, rounded up to 64*... (>=34784)
#define EXP_GRPS (CAP / 64)         // 544
#define LEAK_GRPS (NTOK / 64)       // 256

typedef __attribute__((ext_vector_type(8))) short short8;   // 8 bf16 (4 VGPRs)
typedef __attribute__((ext_vector_type(4))) float f32x4;

__device__ inline unsigned short f2bf(float f) {            // RNE, matches fp32->bf16
    unsigned int u = __float_as_uint(f);
    return (unsigned short)((u + 0x7FFF + ((u >> 16) & 1)) >> 16);
}
__device__ inline float bf2f(unsigned short h) {
    return __uint_as_float(((unsigned int)h) << 16);
}

// ---------------------------------------------------------------------------
// A: blocks 0..31 scale[n]; blocks 32..63 per-block histograms (plain stores);
//    blocks 64..1087 convert x (fp32) -> xb (bf16, RNE), 8 elems/thread.
// ---------------------------------------------------------------------------
__global__ __launch_bounds__(256) void k_prep(const float* __restrict__ ops,
                                              const int* __restrict__ idx,
                                              const float* __restrict__ x,
                                              float* __restrict__ scale,
                                              int* __restrict__ hist2,
                                              unsigned short* __restrict__ xb) {
    if (blockIdx.x < N_OPS) {
        const int n = blockIdx.x;
        const float* W = ops + n * MAT;
        float s = 0.f;
        for (int i = threadIdx.x; i < MAT; i += 256) s += fabsf(W[i]);
        for (int off = 32; off; off >>= 1) s += __shfl_xor(s, off);
        __shared__ float red[4];
        const int lane = threadIdx.x & 63, wid = threadIdx.x >> 6;
        if (lane == 0) red[wid] = s;
        __syncthreads();
        if (threadIdx.x == 0)
            scale[n] = fmaxf((red[0] + red[1] + red[2] + red[3]) / (float)MAT, EPS);
    } else if (blockIdx.x < 64) {
        const int b = blockIdx.x - N_OPS;
        __shared__ int lh[N_OPS];
        if (threadIdx.x < N_OPS) lh[threadIdx.x] = 0;
        __syncthreads();
#pragma unroll
        for (int j = 0; j < 4; ++j)
            atomicAdd(&lh[idx[b * 1024 + j * 256 + threadIdx.x]], 1);
        __syncthreads();
        if (threadIdx.x < N_OPS) hist2[b * N_OPS + threadIdx.x] = lh[threadIdx.x];
    } else {
        const int gid = (blockIdx.x - 64) * 256 + threadIdx.x;  // 0..262143, 8 elems each
        const float4* xp = (const float4*)(x + (size_t)gid * 8);
        float4 a = xp[0], b = xp[1];
        unsigned short o[8] = {f2bf(a.x), f2bf(a.y), f2bf(a.z), f2bf(a.w),
                               f2bf(b.x), f2bf(b.y), f2bf(b.z), f2bf(b.w)};
        ((short8*)xb)[gid] = *(const short8*)o;
    }
}

// ---------------------------------------------------------------------------
// B: single block: 64-aligned expert segment offsets, per-(block,expert) scatter
//    bases, -1 fill of all pad slots.
// ---------------------------------------------------------------------------
__global__ __launch_bounds__(256) void k_scan(const int* __restrict__ hist2,
                                              int* __restrict__ base2,
                                              int* __restrict__ list) {
    __shared__ int hl[1024];
    __shared__ int totl[N_OPS];
    __shared__ int offl[N_OPS + 1];
    for (int i = threadIdx.x; i < 1024; i += 256) hl[i] = hist2[i];
    __syncthreads();
    if (threadIdx.x < N_OPS) {
        int t = 0;
        for (int b = 0; b < 32; ++b) t += hl[b * N_OPS + threadIdx.x];
        totl[threadIdx.x] = t;
    }
    __syncthreads();
    if (threadIdx.x == 0) {
        int run = 0;
        for (int e = 0; e < N_OPS; ++e) { offl[e] = run; run += (totl[e] + 63) & ~63; }
        offl[N_OPS] = run;
    }
    __syncthreads();
    if (threadIdx.x < N_OPS) {
        const int e = threadIdx.x;
        int running = offl[e];
        for (int b = 0; b < 32; ++b) { base2[b * N_OPS + e] = running; running += hl[b * N_OPS + e]; }
        for (int s = running; s < offl[e + 1]; ++s) list[s] = -1;
    }
    for (int s = offl[N_OPS] + (int)threadIdx.x; s < CAP; s += 256) list[s] = -1;
}

// ---------------------------------------------------------------------------
// C: blocks 0..31 quantize expert n to TERNARY bf16 (exact +-1/0; scale applied
//    later in fp32) in MFMA-swizzled B layout wb[e][k>>3][n_out][k&7];
//    blocks 32..63 scatter assignments (LDS atomics only) + inverse map.
// ---------------------------------------------------------------------------
__global__ __launch_bounds__(256) void k_quant_scatter(const float* __restrict__ ops,
                                                       const int* __restrict__ idx,
                                                       const float* __restrict__ scale,
                                                       const int* __restrict__ base2,
                                                       unsigned short* __restrict__ wb,
                                                       int* __restrict__ list,
                                                       int* __restrict__ slot_of) {
    if (blockIdx.x < N_OPS) {
        const int e = blockIdx.x;
        const float sc = scale[e];
        const float* W = ops + e * MAT;
#pragma unroll
        for (int it = 0; it < 8; ++it) {
            const int f = it * 256 + threadIdx.x;   // 2048 (o, dchunk) pairs
            const int o = f >> 4, dc = f & 15;
            const float4* wp = (const float4*)(W + o * D + dc * 8);
            float4 a = wp[0], b = wp[1];
            float v[8] = {a.x, a.y, a.z, a.w, b.x, b.y, b.z, b.w};
            unsigned short q[8];
#pragma unroll
            for (int j = 0; j < 8; ++j) {
                float t = rintf(v[j] / sc);                 // true divide: ref boundary
                t = fminf(1.f, fmaxf(-1.f, t));
                q[j] = (t == 0.f) ? 0 : (t > 0.f ? 0x3F80 : 0xBF80);  // exact bf16 +-1/0
            }
            ((short8*)wb)[e * 2048 + dc * 128 + o] = *(const short8*)q;
        }
    } else {
        const int b = blockIdx.x - N_OPS;
        __shared__ int lh[N_OPS];
        if (threadIdx.x < N_OPS) lh[threadIdx.x] = 0;
        __syncthreads();
#pragma unroll
        for (int j = 0; j < 4; ++j) {
            const int a = b * 1024 + j * 256 + threadIdx.x;
            const int e = idx[a];
            const int r = atomicAdd(&lh[e], 1);
            const int slot = base2[b * N_OPS + e] + r;
            list[slot] = (e << 20) | a;
            slot_of[a] = slot;
        }
    }
}

// ---------------------------------------------------------------------------
// D: leak matrix as "expert 32": wb[32] = bf16( (LEAK/32) * sum_e scale_e*q_e ),
//    elementwise in swizzled space. 8 blocks x 256, 8 elems/thread.
// ---------------------------------------------------------------------------
__global__ __launch_bounds__(256) void k_leak(const unsigned short* __restrict__ wb_c,
                                              const float* __restrict__ scale,
                                              unsigned short* __restrict__ wb) {
    const int gid = blockIdx.x * 256 + threadIdx.x;   // 0..2047 short8 groups
    float acc[8] = {0, 0, 0, 0, 0, 0, 0, 0};
    for (int e = 0; e < N_OPS; ++e) {
        const float se = scale[e];
        short8 v = ((const short8*)wb_c)[e * 2048 + gid];
#pragma unroll
        for (int j = 0; j < 8; ++j) acc[j] += se * bf2f((unsigned short)v[j]);
    }
    unsigned short o[8];
#pragma unroll
    for (int j = 0; j < 8; ++j) o[j] = f2bf(acc[j] * (LEAK / (float)N_OPS));
    ((short8*)wb)[N_OPS * 2048 + gid] = *(const short8*)o;
}

// ---------------------------------------------------------------------------
// E: grouped GEMM via MFMA 16x16x32 bf16. Block = one 64-slot group (one
//    expert) or 64 consecutive tokens (leak). B (32KB) staged in LDS once per
//    block; wave computes a 16(slot) x 128(out) tile = 4 K-steps x 8 N-tiles.
//    Epilogue scales by fp32 scale[e] (leak: 1) and stores plain dwords.
// ---------------------------------------------------------------------------
__global__ __launch_bounds__(256, 2) void k_mfma(const unsigned short* __restrict__ xb,
                                                 const int* __restrict__ list,
                                                 const unsigned short* __restrict__ wb,
                                                 const float* __restrict__ scale,
                                                 float* __restrict__ partial,
                                                 float* __restrict__ out) {
    __shared__ short8 lB[2048];   // 32KB, layout [kq(16)][n_out(128)][kk(8)]
    const int lane = threadIdx.x & 63;
    const int wv   = threadIdx.x >> 6;
    const int quad = lane >> 4;
    const int ncol = lane & 15;

    int gbase;
    const short8* src;
    float sc;
    float* dst;
    bool isleak;
    if (blockIdx.x < EXP_GRPS) {
        gbase = blockIdx.x * 64;
        const int v0 = list[gbase];         // block-uniform (pads only at tails)
        if (v0 < 0) return;                 // fully-pad group
        const int e = v0 >> 20;
        src = (const short8*)wb + e * 2048;
        sc = scale[e];
        dst = partial;
        isleak = false;
    } else {
        gbase = (blockIdx.x - EXP_GRPS) * 64;
        src = (const short8*)wb + N_OPS * 2048;
        sc = 1.f;
        dst = out;
        isleak = true;
    }

    // stage B (straight 32KB copy; layout already MFMA-swizzled)
    for (int i = threadIdx.x; i < 2048; i += 256) lB[i] = src[i];
    __syncthreads();

    // lane's A-row token: row m = ncol of this wave's 16 slots
    int tok;
    if (isleak) {
        tok = gbase + wv * 16 + ncol;
    } else {
        const int v = list[gbase + wv * 16 + ncol];
        tok = (v < 0) ? 0 : ((v & 0xFFFFF) >> 1);   // pad rows compute garbage, never read
    }
    const short8* Ap = (const short8*)(xb + (size_t)tok * D);

    f32x4 acc[8];
#pragma unroll
    for (int j = 0; j < 8; ++j) acc[j] = (f32x4){0.f, 0.f, 0.f, 0.f};

#pragma unroll
    for (int s = 0; s < 4; ++s) {
        const short8 a = Ap[s * 4 + quad];                  // A[m=ncol][k=s*32+quad*8+j]
        const short8* Bp = lB + (s * 4 + quad) * 128;
#pragma unroll
        for (int nt = 0; nt < 8; ++nt) {
            const short8 b = Bp[nt * 16 + ncol];            // B[k][n=nt*16+ncol]
            acc[nt] = __builtin_amdgcn_mfma_f32_16x16x32_bf16(a, b, acc[nt], 0, 0, 0);
        }
    }

    // epilogue: C/D layout col=lane&15, row=quad*4+reg
#pragma unroll
    for (int nt = 0; nt < 8; ++nt) {
#pragma unroll
        for (int r = 0; r < 4; ++r) {
            const int row = gbase + wv * 16 + quad * 4 + r;   // slot (or token for leak)
            dst[(size_t)row * D + nt * 16 + ncol] = acc[nt][r] * sc;
        }
    }
}

// ---------------------------------------------------------------------------
// F: finalize: out[t] = leak(out[t]) + w0*partial[s0] + w1*partial[s1].
// ---------------------------------------------------------------------------
__global__ __launch_bounds__(256) void k_final(const float* __restrict__ partial,
                                               const int* __restrict__ slot_of,
                                               const float* __restrict__ wts,
                                               float* __restrict__ out) {
    const int lane = threadIdx.x & 63;
    const int t = blockIdx.x * 4 + (threadIdx.x >> 6);
    const int s0 = slot_of[2 * t], s1 = slot_of[2 * t + 1];
    const float w0 = wts[2 * t], w1 = wts[2 * t + 1];
    const float2 p0 = ((const float2*)(partial + (size_t)s0 * D))[lane];
    const float2 p1 = ((const float2*)(partial + (size_t)s1 * D))[lane];
    float2* op = ((float2*)out) + (size_t)t * 64 + lane;
    float2 o = *op;
    o.x += w0 * p0.x + w1 * p1.x;
    o.y += w0 * p0.y + w1 * p1.y;
    *op = o;
}

// ---------------------------------------------------------------------------
extern "C" void kernel_launch(void* const* d_in, const int* in_sizes, int n_in,
                              void* d_out, int out_size, void* d_ws, size_t ws_size,
                              hipStream_t stream) {
    const float* x   = (const float*)d_in[0];
    const int*   idx = (const int*)  d_in[1];
    const float* wts = (const float*)d_in[2];
    const float* ops = (const float*)d_in[3];
    float* out = (float*)d_out;

    // ws layout (16B-aligned blocks):
    float*          partial = (float*)d_ws;                       // CAP*128 f32 = 17.8MB
    unsigned short* xb      = (unsigned short*)(partial + (size_t)CAP * D);  // 2M bf16 = 4MB
    unsigned short* wb      = xb + (size_t)NTOK * D;              // 33*16384 bf16
    float*          scale   = (float*)(wb + 33 * MAT);            // 32
    int*            hist2   = (int*)(scale + 32);                 // 1024
    int*            base2   = hist2 + 1024;                       // 1024
    int*            list    = base2 + 1024;                       // CAP
    int*            slot_of = list + CAP;                         // 32768

    k_prep<<<1088, 256, 0, stream>>>(ops, idx, x, scale, hist2, xb);
    k_scan<<<1, 256, 0, stream>>>(hist2, base2, list);
    k_quant_scatter<<<64, 256, 0, stream>>>(ops, idx, scale, base2, wb, list, slot_of);
    k_leak<<<8, 256, 0, stream>>>(wb, scale, wb);
    k_mfma<<<EXP_GRPS + LEAK_GRPS, 256, 0, stream>>>(xb, list, wb, scale, partial, out);
    k_final<<<NTOK / 4, 256, 0, stream>>>(partial, slot_of, wts, out);
}

// Round 5
// 110.305 us; speedup vs baseline: 4.6621x; 1.0238x over previous
//
#include <hip/hip_runtime.h>

#define N_OPS 32
#define D 128
#define MAT (D * D)                 // 16384 elements per matrix
#define EPS 1e-5f
#define LEAK 1e-5f
#define NTOK (8 * 2048)
#define NASSIGN (NTOK * 2)
#define CAP 34816                   // 32768 + 32*63 pad, rounded up
#define EXP_GRPS (CAP / 64)         // 544
#define LEAK_BLKS 64                // 64 blocks x 256 tokens

typedef __attribute__((ext_vector_type(8))) short short8;   // 8 bf16 (4 VGPRs)
typedef __attribute__((ext_vector_type(4))) float f32x4;

__device__ inline unsigned short f2bf(float f) {            // RNE fp32->bf16
    unsigned int u = __float_as_uint(f);
    return (unsigned short)((u + 0x7FFF + ((u >> 16) & 1)) >> 16);
}
__device__ inline float bf2f(unsigned short h) {
    return __uint_as_float(((unsigned int)h) << 16);
}

// ---------------------------------------------------------------------------
// K1: blocks 0..31 scale[n]; 32..63 per-block histograms; 64..1087 x -> bf16.
// ---------------------------------------------------------------------------
__global__ __launch_bounds__(256) void k_prep(const float* __restrict__ ops,
                                              const int* __restrict__ idx,
                                              const float* __restrict__ x,
                                              float* __restrict__ scale,
                                              int* __restrict__ hist2,
                                              unsigned short* __restrict__ xb) {
    if (blockIdx.x < N_OPS) {
        const int n = blockIdx.x;
        const float* W = ops + n * MAT;
        float s = 0.f;
        for (int i = threadIdx.x; i < MAT; i += 256) s += fabsf(W[i]);
        for (int off = 32; off; off >>= 1) s += __shfl_xor(s, off);
        __shared__ float red[4];
        const int lane = threadIdx.x & 63, wid = threadIdx.x >> 6;
        if (lane == 0) red[wid] = s;
        __syncthreads();
        if (threadIdx.x == 0)
            scale[n] = fmaxf((red[0] + red[1] + red[2] + red[3]) / (float)MAT, EPS);
    } else if (blockIdx.x < 64) {
        const int b = blockIdx.x - N_OPS;
        __shared__ int lh[N_OPS];
        if (threadIdx.x < N_OPS) lh[threadIdx.x] = 0;
        __syncthreads();
#pragma unroll
        for (int j = 0; j < 4; ++j)
            atomicAdd(&lh[idx[b * 1024 + j * 256 + threadIdx.x]], 1);
        __syncthreads();
        if (threadIdx.x < N_OPS) hist2[b * N_OPS + threadIdx.x] = lh[threadIdx.x];
    } else {
        const int gid = (blockIdx.x - 64) * 256 + threadIdx.x;  // 8 elems each
        const float4* xp = (const float4*)(x + (size_t)gid * 8);
        float4 a = xp[0], b = xp[1];
        unsigned short o[8] = {f2bf(a.x), f2bf(a.y), f2bf(a.z), f2bf(a.w),
                               f2bf(b.x), f2bf(b.y), f2bf(b.z), f2bf(b.w)};
        ((short8*)xb)[gid] = *(const short8*)o;
    }
}

// ---------------------------------------------------------------------------
// K2: block 0 = scan (segment offsets, scatter bases, -1 pad fill);
//     blocks 1..32 = quantize expert e to ternary bf16 in MFMA-swizzled
//     layout wb[e][k>>3][n_out][k&7]. Scale applied later in fp32.
// ---------------------------------------------------------------------------
__global__ __launch_bounds__(256) void k_scan_quant(const float* __restrict__ ops,
                                                    const float* __restrict__ scale,
                                                    const int* __restrict__ hist2,
                                                    int* __restrict__ base2,
                                                    int* __restrict__ list,
                                                    unsigned short* __restrict__ wb) {
    if (blockIdx.x == 0) {
        __shared__ int hl[1024];
        __shared__ int totl[N_OPS];
        __shared__ int offl[N_OPS + 1];
        for (int i = threadIdx.x; i < 1024; i += 256) hl[i] = hist2[i];
        __syncthreads();
        if (threadIdx.x < N_OPS) {
            int t = 0;
            for (int b = 0; b < 32; ++b) t += hl[b * N_OPS + threadIdx.x];
            totl[threadIdx.x] = t;
        }
        __syncthreads();
        if (threadIdx.x == 0) {
            int run = 0;
            for (int e = 0; e < N_OPS; ++e) { offl[e] = run; run += (totl[e] + 63) & ~63; }
            offl[N_OPS] = run;
        }
        __syncthreads();
        if (threadIdx.x < N_OPS) {
            const int e = threadIdx.x;
            int running = offl[e];
            for (int b = 0; b < 32; ++b) { base2[b * N_OPS + e] = running; running += hl[b * N_OPS + e]; }
            for (int s = running; s < offl[e + 1]; ++s) list[s] = -1;
        }
        for (int s = offl[N_OPS] + (int)threadIdx.x; s < CAP; s += 256) list[s] = -1;
    } else {
        const int e = blockIdx.x - 1;
        const float sc = scale[e];
        const float* W = ops + e * MAT;
#pragma unroll
        for (int it = 0; it < 8; ++it) {
            const int f = it * 256 + threadIdx.x;   // 2048 (o, dchunk) pairs
            const int o = f >> 4, dc = f & 15;
            const float4* wp = (const float4*)(W + o * D + dc * 8);
            float4 a = wp[0], b = wp[1];
            float v[8] = {a.x, a.y, a.z, a.w, b.x, b.y, b.z, b.w};
            unsigned short q[8];
#pragma unroll
            for (int j = 0; j < 8; ++j) {
                float t = rintf(v[j] / sc);                 // true divide: ref boundary
                t = fminf(1.f, fmaxf(-1.f, t));
                q[j] = (t == 0.f) ? 0 : (t > 0.f ? 0x3F80 : 0xBF80);
            }
            ((short8*)wb)[e * 2048 + dc * 128 + o] = *(const short8*)q;
        }
    }
}

// ---------------------------------------------------------------------------
// K3: blocks 0..31 scatter assignments (LDS atomics) + inverse map;
//     blocks 32..95 build leak matrix wb[32] = bf16((LEAK/32)*sum_e sc_e*q_e):
//     thread = (group_local, expert-chunk of 4), shfl_xor reduce across 8.
// ---------------------------------------------------------------------------
__global__ __launch_bounds__(256) void k_scatter_leakmat(const int* __restrict__ idx,
                                                         const float* __restrict__ scale,
                                                         const int* __restrict__ base2,
                                                         int* __restrict__ list,
                                                         int* __restrict__ slot_of,
                                                         unsigned short* __restrict__ wb) {
    if (blockIdx.x < 32) {
        const int b = blockIdx.x;
        __shared__ int lh[N_OPS];
        if (threadIdx.x < N_OPS) lh[threadIdx.x] = 0;
        __syncthreads();
#pragma unroll
        for (int j = 0; j < 4; ++j) {
            const int a = b * 1024 + j * 256 + threadIdx.x;
            const int e = idx[a];
            const int r = atomicAdd(&lh[e], 1);
            const int slot = base2[b * N_OPS + e] + r;
            list[slot] = (e << 20) | a;
            slot_of[a] = slot;
        }
    } else {
        const int lb = blockIdx.x - 32;                  // 0..63
        const int g  = lb * 32 + (threadIdx.x >> 3);     // short8 group 0..2047
        const int ec = threadIdx.x & 7;                  // expert chunk: 4 experts
        float acc[8] = {0, 0, 0, 0, 0, 0, 0, 0};
#pragma unroll
        for (int ee = 0; ee < 4; ++ee) {
            const int e = ec * 4 + ee;
            const float se = scale[e];
            short8 v = ((const short8*)wb)[e * 2048 + g];
#pragma unroll
            for (int j = 0; j < 8; ++j) acc[j] += se * bf2f((unsigned short)v[j]);
        }
#pragma unroll
        for (int m = 1; m <= 4; m <<= 1)
#pragma unroll
            for (int j = 0; j < 8; ++j) acc[j] += __shfl_xor(acc[j], m);
        if (ec == 0) {
            unsigned short o[8];
#pragma unroll
            for (int j = 0; j < 8; ++j) o[j] = f2bf(acc[j] * (LEAK / (float)N_OPS));
            ((short8*)wb)[N_OPS * 2048 + g] = *(const short8*)o;
        }
    }
}

// ---------------------------------------------------------------------------
// K4: grouped GEMM, MFMA 16x16x32 bf16. Blocks [0,544): one 64-slot expert
// group -> partial. Blocks [544,608): 256 consecutive tokens through the leak
// matrix -> out (B staged ONCE per 256 tokens). B = 32KB in LDS, pre-swizzled.
// ---------------------------------------------------------------------------
__global__ __launch_bounds__(256, 2) void k_mfma(const unsigned short* __restrict__ xb,
                                                 const int* __restrict__ list,
                                                 const unsigned short* __restrict__ wb,
                                                 const float* __restrict__ scale,
                                                 float* __restrict__ partial,
                                                 float* __restrict__ out) {
    __shared__ short8 lB[2048];   // [kq(16)][n_out(128)][kk(8)]
    const int lane = threadIdx.x & 63;
    const int wv   = threadIdx.x >> 6;
    const int quad = lane >> 4;
    const int ncol = lane & 15;

    const bool isleak = blockIdx.x >= EXP_GRPS;
    const short8* src;
    if (isleak) {
        src = (const short8*)wb + N_OPS * 2048;
    } else {
        const int v0 = list[blockIdx.x * 64];   // block-uniform expert
        if (v0 < 0) return;                     // fully-pad tail group
        src = (const short8*)wb + (v0 >> 20) * 2048;
    }
    for (int i = threadIdx.x; i < 2048; i += 256) lB[i] = src[i];
    __syncthreads();

    const int npass = isleak ? 4 : 1;
    for (int g = 0; g < npass; ++g) {
        int rowbase, tok;
        float sc;
        float* dst;
        if (isleak) {
            rowbase = (blockIdx.x - EXP_GRPS) * 256 + g * 64 + wv * 16;
            tok = rowbase + ncol;
            sc = 1.f;
            dst = out;
        } else {
            rowbase = blockIdx.x * 64 + wv * 16;
            const int v = list[rowbase + ncol];
            tok = (v < 0) ? 0 : ((v & 0xFFFFF) >> 1);   // pad rows: garbage, never read
            sc = scale[__builtin_amdgcn_readfirstlane(list[blockIdx.x * 64]) >> 20];
            dst = partial;
        }
        const short8* Ap = (const short8*)(xb + (size_t)tok * D);

        f32x4 acc[8];
#pragma unroll
        for (int j = 0; j < 8; ++j) acc[j] = (f32x4){0.f, 0.f, 0.f, 0.f};

#pragma unroll
        for (int s = 0; s < 4; ++s) {
            const short8 a = Ap[s * 4 + quad];              // A[m=ncol][k=s*32+quad*8+j]
            const short8* Bp = lB + (s * 4 + quad) * 128;
#pragma unroll
            for (int nt = 0; nt < 8; ++nt) {
                const short8 b = Bp[nt * 16 + ncol];        // B[k][n=nt*16+ncol]
                acc[nt] = __builtin_amdgcn_mfma_f32_16x16x32_bf16(a, b, acc[nt], 0, 0, 0);
            }
        }
        // C/D layout: col = lane&15, row = quad*4 + reg
#pragma unroll
        for (int nt = 0; nt < 8; ++nt)
#pragma unroll
            for (int r = 0; r < 4; ++r)
                dst[(size_t)(rowbase + quad * 4 + r) * D + nt * 16 + ncol] = acc[nt][r] * sc;
    }
}

// ---------------------------------------------------------------------------
// K5: finalize: out[t] = leak(out[t]) + w0*partial[s0] + w1*partial[s1].
// ---------------------------------------------------------------------------
__global__ __launch_bounds__(256) void k_final(const float* __restrict__ partial,
                                               const int* __restrict__ slot_of,
                                               const float* __restrict__ wts,
                                               float* __restrict__ out) {
    const int lane = threadIdx.x & 63;
    const int t = blockIdx.x * 4 + (threadIdx.x >> 6);
    const int s0 = slot_of[2 * t], s1 = slot_of[2 * t + 1];
    const float w0 = wts[2 * t], w1 = wts[2 * t + 1];
    const float2 p0 = ((const float2*)(partial + (size_t)s0 * D))[lane];
    const float2 p1 = ((const float2*)(partial + (size_t)s1 * D))[lane];
    float2* op = ((float2*)out) + (size_t)t * 64 + lane;
    float2 o = *op;
    o.x += w0 * p0.x + w1 * p1.x;
    o.y += w0 * p0.y + w1 * p1.y;
    *op = o;
}

// ---------------------------------------------------------------------------
extern "C" void kernel_launch(void* const* d_in, const int* in_sizes, int n_in,
                              void* d_out, int out_size, void* d_ws, size_t ws_size,
                              hipStream_t stream) {
    const float* x   = (const float*)d_in[0];
    const int*   idx = (const int*)  d_in[1];
    const float* wts = (const float*)d_in[2];
    const float* ops = (const float*)d_in[3];
    float* out = (float*)d_out;

    float*          partial = (float*)d_ws;                                  // CAP*128 f32
    unsigned short* xb      = (unsigned short*)(partial + (size_t)CAP * D);  // 2M bf16
    unsigned short* wb      = xb + (size_t)NTOK * D;                         // 33*16384 bf16
    float*          scale   = (float*)(wb + 33 * MAT);
    int*            hist2   = (int*)(scale + 32);
    int*            base2   = hist2 + 1024;
    int*            list    = base2 + 1024;
    int*            slot_of = list + CAP;

    k_prep<<<1088, 256, 0, stream>>>(ops, idx, x, scale, hist2, xb);
    k_scan_quant<<<33, 256, 0, stream>>>(ops, scale, hist2, base2, list, wb);
    k_scatter_leakmat<<<96, 256, 0, stream>>>(idx, scale, base2, list, slot_of, wb);
    k_mfma<<<EXP_GRPS + LEAK_BLKS, 256, 0, stream>>>(xb, list, wb, scale, partial, out);
    k_final<<<NTOK / 4, 256, 0, stream>>>(partial, slot_of, wts, out);
}